// Round 1
// baseline (60.051 us; speedup 1.0000x reference)
//
#include <hip/hip_runtime.h>

// Problem constants (match reference setup_inputs)
#define BATCH 2048
#define NPTS  8192

// convert_to_radar_frame constants
// cart_min_range = (640/2 - 0.5) * 0.2592
#define RES 0.2592f
#define CMR 82.8144f

__device__ __forceinline__ float wave_reduce_add(float v) {
    #pragma unroll
    for (int off = 32; off > 0; off >>= 1) v += __shfl_down(v, off, 64);
    return v;
}

__global__ __launch_bounds__(256, 4) void svd_align_kernel(
    const float* __restrict__ src, const float* __restrict__ tgt,
    const float* __restrict__ wts, const int* __restrict__ cvt_flag,
    float* __restrict__ out)
{
    const int b   = blockIdx.x;
    const int tid = threadIdx.x;
    const int convert = *cvt_flag;  // wave-uniform branch

    const float4* s4  = (const float4*)(src + (size_t)b * NPTS * 2);
    const float4* t4  = (const float4*)(tgt + (size_t)b * NPTS * 2);
    const float2* w2p = (const float2*)(wts + (size_t)b * NPTS);

    // 9 accumulators: sum w, sum w*sx, w*sy, w*tx, w*ty, w*tx*sx, w*tx*sy, w*ty*sx, w*ty*sy
    float aW = 0.f, aSx = 0.f, aSy = 0.f, aTx = 0.f, aTy = 0.f;
    float aXX = 0.f, aXY = 0.f, aYX = 0.f, aYY = 0.f;

    // 16 iterations x (2 points/thread): perfectly coalesced float4/float2 streams
    #pragma unroll 4
    for (int i = 0; i < 16; ++i) {
        const int k = i * 256 + tid;          // float4 index into [N*2] floats
        float4 s = s4[k];
        float4 t = t4[k];
        float2 w = w2p[k];

        float sx0, sy0, sx1, sy1, tx0, ty0, tx1, ty1;
        if (convert) {
            sx0 = fmaf(-RES, s.y, CMR);  sy0 = fmaf(RES, s.x, -CMR);
            sx1 = fmaf(-RES, s.w, CMR);  sy1 = fmaf(RES, s.z, -CMR);
            tx0 = fmaf(-RES, t.y, CMR);  ty0 = fmaf(RES, t.x, -CMR);
            tx1 = fmaf(-RES, t.w, CMR);  ty1 = fmaf(RES, t.z, -CMR);
        } else {
            sx0 = s.x; sy0 = s.y; sx1 = s.z; sy1 = s.w;
            tx0 = t.x; ty0 = t.y; tx1 = t.z; ty1 = t.w;
        }

        // point 0
        {
            float wv = w.x;
            float wtx = wv * tx0, wty = wv * ty0;
            aW  += wv;
            aSx = fmaf(wv, sx0, aSx);  aSy = fmaf(wv, sy0, aSy);
            aTx += wtx;                aTy += wty;
            aXX = fmaf(wtx, sx0, aXX); aXY = fmaf(wtx, sy0, aXY);
            aYX = fmaf(wty, sx0, aYX); aYY = fmaf(wty, sy0, aYY);
        }
        // point 1
        {
            float wv = w.y;
            float wtx = wv * tx1, wty = wv * ty1;
            aW  += wv;
            aSx = fmaf(wv, sx1, aSx);  aSy = fmaf(wv, sy1, aSy);
            aTx += wtx;                aTy += wty;
            aXX = fmaf(wtx, sx1, aXX); aXY = fmaf(wtx, sy1, aXY);
            aYX = fmaf(wty, sx1, aYX); aYY = fmaf(wty, sy1, aYY);
        }
    }

    // wave64 reduce each accumulator
    aW  = wave_reduce_add(aW);
    aSx = wave_reduce_add(aSx);  aSy = wave_reduce_add(aSy);
    aTx = wave_reduce_add(aTx);  aTy = wave_reduce_add(aTy);
    aXX = wave_reduce_add(aXX);  aXY = wave_reduce_add(aXY);
    aYX = wave_reduce_add(aYX);  aYY = wave_reduce_add(aYY);

    __shared__ float red[4][9];
    const int wave = tid >> 6;
    if ((tid & 63) == 0) {
        red[wave][0] = aW;
        red[wave][1] = aSx; red[wave][2] = aSy;
        red[wave][3] = aTx; red[wave][4] = aTy;
        red[wave][5] = aXX; red[wave][6] = aXY;
        red[wave][7] = aYX; red[wave][8] = aYY;
    }
    __syncthreads();

    if (tid == 0) {
        double Sw = 0, Ssx = 0, Ssy = 0, Stx = 0, Sty = 0;
        double Sxx = 0, Sxy = 0, Syx = 0, Syy = 0;
        #pragma unroll
        for (int i = 0; i < 4; ++i) {
            Sw  += red[i][0];
            Ssx += red[i][1]; Ssy += red[i][2];
            Stx += red[i][3]; Sty += red[i][4];
            Sxx += red[i][5]; Sxy += red[i][6];
            Syx += red[i][7]; Syy += red[i][8];
        }

        const double wd  = Sw + 1e-4;
        const double scx = Ssx / wd, scy = Ssy / wd;
        const double tcx = Stx / wd, tcy = Sty / wd;

        // W[d][e] = (sum w*t_d*s_e - tc_d*sum(w s_e) - sc_e*sum(w t_d) + tc_d*sc_e*Sw)/wd
        const double W00 = (Sxx - tcx * Ssx - scx * Stx + tcx * scx * Sw) / wd;
        const double W01 = (Sxy - tcx * Ssy - scy * Stx + tcx * scy * Sw) / wd;
        const double W10 = (Syx - tcy * Ssx - scx * Sty + tcy * scx * Sw) / wd;
        const double W11 = (Syy - tcy * Ssy - scy * Sty + tcy * scy * Sw) / wd;

        const double det = W00 * W11 - W01 * W10;

        // 2x2 orthogonal polar factor of W (== U2 @ V2^T from SVD), plus
        // R[2][2] = sign(det) from the Kabsch diag(1,1,detU*detV) correction.
        double R00, R01, R10, R11, dsign;
        if (det >= 0.0) {
            const double p = W00 + W11;
            const double q = W10 - W01;
            double r = sqrt(p * p + q * q);
            if (r > 0.0) {
                R00 = p / r;  R01 = -q / r;
                R10 = q / r;  R11 = p / r;
            } else {
                R00 = 1.0; R01 = 0.0; R10 = 0.0; R11 = 1.0;
            }
            dsign = 1.0;
        } else {
            const double p = W00 - W11;
            const double q = W01 + W10;
            const double r = sqrt(p * p + q * q);  // > 0 when det < 0
            R00 = p / r;   R01 = q / r;
            R10 = q / r;   R11 = -p / r;
            dsign = -1.0;
        }

        // t_tgt_src_insrc = src_centroid - R^T @ tgt_centroid (z == 0)
        const double tt0 = scx - (R00 * tcx + R10 * tcy);
        const double tt1 = scy - (R01 * tcx + R11 * tcy);
        // t_src_tgt_intgt = -R @ t_tgt_src_insrc
        const double o0 = -(R00 * tt0 + R01 * tt1);
        const double o1 = -(R10 * tt0 + R11 * tt1);

        // Output 0: R^T, row-major [3][3]
        float* oR = out + (size_t)b * 9;
        oR[0] = (float)R00; oR[1] = (float)R10; oR[2] = 0.f;
        oR[3] = (float)R01; oR[4] = (float)R11; oR[5] = 0.f;
        oR[6] = 0.f;        oR[7] = 0.f;        oR[8] = (float)dsign;

        // Output 1: translation [3][1]
        float* oT = out + (size_t)BATCH * 9 + (size_t)b * 3;
        oT[0] = (float)o0; oT[1] = (float)o1; oT[2] = 0.f;
    }
}

extern "C" void kernel_launch(void* const* d_in, const int* in_sizes, int n_in,
                              void* d_out, int out_size, void* d_ws, size_t ws_size,
                              hipStream_t stream) {
    const float* src = (const float*)d_in[0];
    const float* tgt = (const float*)d_in[1];
    const float* wts = (const float*)d_in[2];
    const int*   cvt = (const int*)d_in[3];
    float* out = (float*)d_out;

    svd_align_kernel<<<BATCH, 256, 0, stream>>>(src, tgt, wts, cvt, out);
}